// Round 1
// baseline (388.620 us; speedup 1.0000x reference)
//
#include <hip/hip_runtime.h>

#define Bsz 64
#define Lsz 4096
#define Dsz 512
#define Hsz 512
#define Usz 256

typedef __attribute__((ext_vector_type(8))) short s8v;     // bf16x8 MFMA frag
typedef __attribute__((ext_vector_type(4))) float f4v;
typedef __attribute__((ext_vector_type(4))) unsigned short u16x4;

__device__ __forceinline__ unsigned short f2bf(float f) {
    unsigned int u = __float_as_uint(f);
    u += 0x7FFFu + ((u >> 16) & 1u);   // round-to-nearest-even
    return (unsigned short)(u >> 16);
}

// ws layout
//   [0, 256KiB)          : W1T bf16 [256][512]
//   [256KiB, 320KiB)     : hproj f32 [64][256]  (includes W2_b + W1_b)
//   [320KiB, 320KiB+1MiB): scores f32 [64][4096]

__global__ void k_prep_w1t(const float* __restrict__ W1, unsigned short* __restrict__ W1T) {
    int e = blockIdx.x * 256 + threadIdx.x;   // 0..131071, coalesced read
    int k = e >> 8;
    int u = e & 255;
    W1T[u * Dsz + k] = f2bf(W1[e]);
}

__global__ void k_hproj(const float* __restrict__ hidden, const float* __restrict__ W2,
                        const float* __restrict__ W2b, const float* __restrict__ W1b,
                        float* __restrict__ hproj) {
    int b = blockIdx.x, u = threadIdx.x;
    float acc = W2b[u] + W1b[u];
    const float* hrow = hidden + (size_t)b * Hsz;
    for (int k = 0; k < Hsz; ++k)
        acc = fmaf(hrow[k], W2[(size_t)k * Usz + u], acc);
    hproj[b * Usz + u] = acc;
}

// Main fused kernel: score[b,l] = tanh(features@W1 + hproj) . V + Vb
// block: 512 thr (8 waves). tile: 128 L-rows x 256 U-cols, K=512 in 8 steps of 64.
// wave w owns U-cols [w*32, w*32+32).
__global__ __launch_bounds__(512, 2) void k_score(
    const float* __restrict__ feat, const unsigned short* __restrict__ W1T,
    const float* __restrict__ hproj, const float* __restrict__ Vk,
    const float* __restrict__ Vb, float* __restrict__ scores)
{
    __shared__ unsigned short Atile[128][72];   // +8 pad -> 144B row stride (16B-aligned)
    __shared__ float hp[Usz];
    __shared__ float vv[Usz];
    __shared__ float spart[8][128];

    const int tid  = threadIdx.x;
    const int w    = tid >> 6;
    const int lane = tid & 63;
    const int lr   = lane & 15;     // row (A) / col (B) within fragment
    const int lg   = lane >> 4;     // k-group
    const int b    = blockIdx.y;
    const int l0   = blockIdx.x * 128;

    if (tid < Usz) { hp[tid] = hproj[b * Usz + tid]; vv[tid] = Vk[tid]; }

    f4v acc[8][2];
#pragma unroll
    for (int i = 0; i < 8; ++i) {
        acc[i][0] = (f4v){0.f, 0.f, 0.f, 0.f};
        acc[i][1] = (f4v){0.f, 0.f, 0.f, 0.f};
    }

    for (int kt = 0; kt < 8; ++kt) {
        const int k0 = kt * 64;
        // stage A tile: 128 rows x 64 k (fp32 -> bf16)
#pragma unroll
        for (int i = 0; i < 4; ++i) {
            int q = i * 512 + tid;          // float4 index, 0..2047
            int row = q >> 4, c4 = (q & 15) * 4;
            f4v v = *reinterpret_cast<const f4v*>(
                feat + (size_t)(b * Lsz + l0 + row) * Dsz + k0 + c4);
            u16x4 o = { f2bf(v.x), f2bf(v.y), f2bf(v.z), f2bf(v.w) };
            *reinterpret_cast<u16x4*>(&Atile[row][c4]) = o;
        }
        __syncthreads();

        // B fragments straight from global (W1T is L2-resident)
        s8v bfr[2][2];
#pragma unroll
        for (int nf = 0; nf < 2; ++nf)
#pragma unroll
            for (int ks = 0; ks < 2; ++ks)
                bfr[nf][ks] = *reinterpret_cast<const s8v*>(
                    W1T + (size_t)(w * 32 + nf * 16 + lr) * Dsz + k0 + ks * 32 + lg * 8);

#pragma unroll
        for (int ks = 0; ks < 2; ++ks) {
#pragma unroll
            for (int mf = 0; mf < 8; ++mf) {
                s8v a = *reinterpret_cast<const s8v*>(&Atile[mf * 16 + lr][ks * 32 + lg * 8]);
                acc[mf][0] = __builtin_amdgcn_mfma_f32_16x16x32_bf16(a, bfr[0][ks], acc[mf][0], 0, 0, 0);
                acc[mf][1] = __builtin_amdgcn_mfma_f32_16x16x32_bf16(a, bfr[1][ks], acc[mf][1], 0, 0, 0);
            }
        }
        __syncthreads();
    }

    // epilogue: rs[mf][r] = sum over this wave's 32 cols of tanh(x)*V
    float rs[8][4];
#pragma unroll
    for (int mf = 0; mf < 8; ++mf)
#pragma unroll
        for (int r = 0; r < 4; ++r) rs[mf][r] = 0.f;

#pragma unroll
    for (int mf = 0; mf < 8; ++mf) {
#pragma unroll
        for (int nf = 0; nf < 2; ++nf) {
            int col = w * 32 + nf * 16 + lr;
            float hpv = hp[col], vvv = vv[col];
#pragma unroll
            for (int r = 0; r < 4; ++r) {
                float x = acc[mf][nf][r] + hpv;
                float e = __expf(2.f * x);
                float t = 1.f - 2.f / (e + 1.f);     // tanh(x), safe at +/-inf
                rs[mf][r] = fmaf(t, vvv, rs[mf][r]);
            }
        }
    }
    // reduce across the 16 lanes that share a row group (low 4 lane bits = col)
#pragma unroll
    for (int off = 1; off < 16; off <<= 1)
#pragma unroll
        for (int mf = 0; mf < 8; ++mf)
#pragma unroll
            for (int r = 0; r < 4; ++r)
                rs[mf][r] += __shfl_xor(rs[mf][r], off, 64);

    if (lr == 0) {
#pragma unroll
        for (int mf = 0; mf < 8; ++mf)
#pragma unroll
            for (int r = 0; r < 4; ++r)
                spart[w][mf * 16 + lg * 4 + r] = rs[mf][r];
    }
    __syncthreads();
    if (tid < 128) {
        float s = Vb[0];
#pragma unroll
        for (int ww = 0; ww < 8; ++ww) s += spart[ww][tid];
        scores[(size_t)b * Lsz + l0 + tid] = s;
    }
}

__global__ __launch_bounds__(256) void k_softmax(const float* __restrict__ scores,
                                                 float* __restrict__ wout) {
    __shared__ float srow[Lsz];
    __shared__ float red[8];
    int b = blockIdx.x, tid = threadIdx.x;
    float m = -1e30f;
#pragma unroll
    for (int i = 0; i < Lsz / 256; ++i) {
        float v = scores[(size_t)b * Lsz + i * 256 + tid];
        srow[i * 256 + tid] = v;
        m = fmaxf(m, v);
    }
#pragma unroll
    for (int off = 1; off < 64; off <<= 1) m = fmaxf(m, __shfl_xor(m, off, 64));
    if ((tid & 63) == 0) red[tid >> 6] = m;
    __syncthreads();
    m = fmaxf(fmaxf(red[0], red[1]), fmaxf(red[2], red[3]));
    float s = 0.f;
#pragma unroll
    for (int i = 0; i < Lsz / 256; ++i) s += __expf(srow[i * 256 + tid] - m);
#pragma unroll
    for (int off = 1; off < 64; off <<= 1) s += __shfl_xor(s, off, 64);
    if ((tid & 63) == 0) red[4 + (tid >> 6)] = s;
    __syncthreads();
    float inv = 1.f / (red[4] + red[5] + red[6] + red[7]);
#pragma unroll
    for (int i = 0; i < Lsz / 256; ++i)
        wout[(size_t)b * Lsz + i * 256 + tid] = __expf(srow[i * 256 + tid] - m) * inv;
}

// context[b,d] = sum_l w[b,l] * features[b,l,d]; 256 L-rows per block
__global__ __launch_bounds__(128) void k_context(const float* __restrict__ feat,
                                                 const float* __restrict__ wts,
                                                 float* __restrict__ ctx) {
    __shared__ float wl[256];
    int b = blockIdx.y, l0 = blockIdx.x * 256;
    int tid = threadIdx.x;
    wl[tid] = wts[(size_t)b * Lsz + l0 + tid];
    wl[tid + 128] = wts[(size_t)b * Lsz + l0 + tid + 128];
    __syncthreads();
    f4v acc = (f4v){0.f, 0.f, 0.f, 0.f};
    const float* fbase = feat + (size_t)(b * Lsz + l0) * Dsz + tid * 4;
#pragma unroll 4
    for (int l = 0; l < 256; ++l) {
        f4v v = *reinterpret_cast<const f4v*>(fbase + (size_t)l * Dsz);
        float wv = wl[l];
        acc.x = fmaf(wv, v.x, acc.x);
        acc.y = fmaf(wv, v.y, acc.y);
        acc.z = fmaf(wv, v.z, acc.z);
        acc.w = fmaf(wv, v.w, acc.w);
    }
    float* c = ctx + (size_t)b * Dsz + tid * 4;
    atomicAdd(c + 0, acc.x);
    atomicAdd(c + 1, acc.y);
    atomicAdd(c + 2, acc.z);
    atomicAdd(c + 3, acc.w);
}

extern "C" void kernel_launch(void* const* d_in, const int* in_sizes, int n_in,
                              void* d_out, int out_size, void* d_ws, size_t ws_size,
                              hipStream_t stream) {
    const float* feat   = (const float*)d_in[0];
    const float* hidden = (const float*)d_in[1];
    const float* W1     = (const float*)d_in[2];
    const float* W1b    = (const float*)d_in[3];
    const float* W2     = (const float*)d_in[4];
    const float* W2b    = (const float*)d_in[5];
    const float* Vk     = (const float*)d_in[6];
    const float* Vb     = (const float*)d_in[7];

    unsigned short* w1t = (unsigned short*)d_ws;
    float* hproj  = (float*)((char*)d_ws + 256 * 1024);
    float* scores = (float*)((char*)d_ws + 320 * 1024);

    float* ctx  = (float*)d_out;              // [64, 512]
    float* wout = ctx + Bsz * Dsz;            // [64, 4096, 1]

    hipMemsetAsync(ctx, 0, Bsz * Dsz * sizeof(float), stream);
    k_prep_w1t<<<512, 256, 0, stream>>>(W1, w1t);
    k_hproj<<<Bsz, Usz, 0, stream>>>(hidden, W2, W2b, W1b, hproj);
    k_score<<<dim3(Lsz / 128, Bsz), 512, 0, stream>>>(feat, w1t, hproj, Vk, Vb, scores);
    k_softmax<<<Bsz, 256, 0, stream>>>(scores, wout);
    k_context<<<dim3(Lsz / 256, Bsz), 128, 0, stream>>>(feat, wout, ctx);
}

// Round 2
// 235.391 us; speedup vs baseline: 1.6509x; 1.6509x over previous
//
#include <hip/hip_runtime.h>

#define Bsz 64
#define Lsz 4096
#define Dsz 512
#define Hsz 512
#define Usz 256
#define LT  64            // L-rows per block
#define AW  (Dsz + 8)     // LDS row stride in shorts: 520 -> 1040B (16B-aligned, ~2-way banks)

typedef __attribute__((ext_vector_type(8))) short s8v;     // bf16x8 MFMA frag
typedef __attribute__((ext_vector_type(4))) float f4v;
typedef __attribute__((ext_vector_type(4))) unsigned short u16x4;

__device__ __forceinline__ unsigned short f2bf(float f) {
    unsigned int u = __float_as_uint(f);
    u += 0x7FFFu + ((u >> 16) & 1u);   // round-to-nearest-even
    return (unsigned short)(u >> 16);
}
__device__ __forceinline__ float bf2f(unsigned int lo16) {
    return __uint_as_float(lo16 << 16);
}

// ws layout
//   [0,      256K)   : W1T bf16 [256][512]
//   [256K,   320K)   : hproj f32 [64][256]  (includes W2_b + W1_b)
//   [320K,  1344K)   : scores f32 [64][4096]
//   [1344K, 1472K)   : ctx_acc f32 [64][512]
//   [1472K, +256B)   : den f32 [64]

__global__ void k_prep_w1t(const float* __restrict__ W1, unsigned short* __restrict__ W1T) {
    int e = blockIdx.x * 256 + threadIdx.x;   // coalesced read of W1 [512][256]
    int k = e >> 8;
    int u = e & 255;
    W1T[u * Dsz + k] = f2bf(W1[e]);
}

__global__ void k_hproj(const float* __restrict__ hidden, const float* __restrict__ W2,
                        const float* __restrict__ W2b, const float* __restrict__ W1b,
                        float* __restrict__ hproj) {
    int b = blockIdx.x, u = threadIdx.x;
    const float* hrow = hidden + (size_t)b * Hsz;
    float a0 = W2b[u] + W1b[u], a1 = 0.f, a2 = 0.f, a3 = 0.f;
#pragma unroll 4
    for (int k = 0; k < Hsz; k += 4) {
        a0 = fmaf(hrow[k + 0], W2[(size_t)(k + 0) * Usz + u], a0);
        a1 = fmaf(hrow[k + 1], W2[(size_t)(k + 1) * Usz + u], a1);
        a2 = fmaf(hrow[k + 2], W2[(size_t)(k + 2) * Usz + u], a2);
        a3 = fmaf(hrow[k + 3], W2[(size_t)(k + 3) * Usz + u], a3);
    }
    hproj[b * Usz + u] = (a0 + a1) + (a2 + a3);
}

// Fused: per block (b, 64 L-rows):
//   s_l   = tanh(feat@W1 + hproj) . V + Vb          -> scores (for weights output)
//   e_l   = exp(s_l)   (no max needed: |s| <= ~8, no overflow)
//   den[b]        += sum_l e_l                       (atomic)
//   ctx_acc[b,d]  += sum_l e_l * feat[l,d]           (atomic, feat from LDS bf16)
// 256 thr (4 waves), wave w owns U-cols [w*64, w*64+64). K=512 fully in LDS.
__global__ __launch_bounds__(256, 2) void k_score_ctx(
    const float* __restrict__ feat, const unsigned short* __restrict__ W1T,
    const float* __restrict__ hproj, const float* __restrict__ Vk,
    const float* __restrict__ Vb, float* __restrict__ scores,
    float* __restrict__ ctx_acc, float* __restrict__ den)
{
    __shared__ __align__(16) unsigned short A[LT][AW];
    __shared__ float hp[Usz];
    __shared__ float vv[Usz];
    __shared__ float spart[4][LT];
    __shared__ float el[LT];

    const int tid  = threadIdx.x;
    const int w    = tid >> 6;
    const int lane = tid & 63;
    const int lr   = lane & 15;
    const int lg   = lane >> 4;
    const int b    = blockIdx.y;
    const int l0   = blockIdx.x * LT;

    if (tid < Usz) { hp[tid] = hproj[b * Usz + tid]; vv[tid] = Vk[tid]; }

    // ---- stage full 64x512 tile (fp32 -> bf16), contiguous 128KB read ----
    const float* fb = feat + (size_t)(b * Lsz + l0) * Dsz;
#pragma unroll 8
    for (int i = 0; i < 32; ++i) {
        int q = i * 256 + tid;            // float4 index over 64*128
        int row = q >> 7, c4 = (q & 127) * 4;
        f4v v = *reinterpret_cast<const f4v*>(fb + (size_t)row * Dsz + c4);
        u16x4 o = { f2bf(v.x), f2bf(v.y), f2bf(v.z), f2bf(v.w) };
        *reinterpret_cast<u16x4*>(&A[row][c4]) = o;
    }
    __syncthreads();

    // ---- GEMM: 64x64 (this wave's cols) x K=512 ----
    f4v acc[4][4];
#pragma unroll
    for (int mf = 0; mf < 4; ++mf)
#pragma unroll
        for (int nf = 0; nf < 4; ++nf) acc[mf][nf] = (f4v){0.f, 0.f, 0.f, 0.f};

    for (int ks = 0; ks < 16; ++ks) {
        const int kof = ks * 32 + lg * 8;
        s8v bf[4];
#pragma unroll
        for (int nf = 0; nf < 4; ++nf)
            bf[nf] = *reinterpret_cast<const s8v*>(
                W1T + (size_t)(w * 64 + nf * 16 + lr) * Dsz + kof);
#pragma unroll
        for (int mf = 0; mf < 4; ++mf) {
            s8v a = *reinterpret_cast<const s8v*>(&A[mf * 16 + lr][kof]);
#pragma unroll
            for (int nf = 0; nf < 4; ++nf)
                acc[mf][nf] = __builtin_amdgcn_mfma_f32_16x16x32_bf16(a, bf[nf], acc[mf][nf], 0, 0, 0);
        }
    }

    // ---- epilogue: per-row sum over this wave's 64 cols of tanh(x)*V ----
    float rs[4][4];
#pragma unroll
    for (int mf = 0; mf < 4; ++mf)
#pragma unroll
        for (int r = 0; r < 4; ++r) rs[mf][r] = 0.f;

#pragma unroll
    for (int mf = 0; mf < 4; ++mf) {
#pragma unroll
        for (int nf = 0; nf < 4; ++nf) {
            int col = w * 64 + nf * 16 + lr;
            float hpv = hp[col], vvv = vv[col];
#pragma unroll
            for (int r = 0; r < 4; ++r) {
                float x = acc[mf][nf][r] + hpv;
                float e = __expf(2.f * x);
                float t = 1.f - 2.f / (e + 1.f);     // tanh, safe at +/-inf
                rs[mf][r] = fmaf(t, vvv, rs[mf][r]);
            }
        }
    }
#pragma unroll
    for (int off = 1; off < 16; off <<= 1)
#pragma unroll
        for (int mf = 0; mf < 4; ++mf)
#pragma unroll
            for (int r = 0; r < 4; ++r)
                rs[mf][r] += __shfl_xor(rs[mf][r], off, 64);

    if (lr == 0) {
#pragma unroll
        for (int mf = 0; mf < 4; ++mf)
#pragma unroll
            for (int r = 0; r < 4; ++r)
                spart[w][mf * 16 + lg * 4 + r] = rs[mf][r];
    }
    __syncthreads();

    // ---- scores, exp, denominator (tid<64 == wave 0) ----
    if (tid < LT) {
        float s = Vb[0] + spart[0][tid] + spart[1][tid] + spart[2][tid] + spart[3][tid];
        scores[(size_t)b * Lsz + l0 + tid] = s;
        float e = __expf(s);
        el[tid] = e;
        float esum = e;
#pragma unroll
        for (int off = 1; off < 64; off <<= 1) esum += __shfl_xor(esum, off, 64);
        if (tid == 0) atomicAdd(&den[b], esum);
    }
    __syncthreads();

    // ---- partial context from the LDS tile: pctx[d] = sum_l e_l * feat[l,d] ----
    {
        const int d0 = tid * 2;
        float a0 = 0.f, a1 = 0.f;
#pragma unroll 8
        for (int l = 0; l < LT; ++l) {
            unsigned int pk = *reinterpret_cast<const unsigned int*>(&A[l][d0]);
            float e = el[l];
            a0 = fmaf(e, bf2f(pk & 0xFFFFu), a0);
            a1 = fmaf(e, bf2f(pk >> 16), a1);
        }
        atomicAdd(&ctx_acc[b * Dsz + d0],     a0);
        atomicAdd(&ctx_acc[b * Dsz + d0 + 1], a1);
    }
}

__global__ __launch_bounds__(256) void k_finalize(const float* __restrict__ scores,
                                                  const float* __restrict__ ctx_acc,
                                                  const float* __restrict__ den,
                                                  float* __restrict__ ctx,
                                                  float* __restrict__ wout) {
    int b = blockIdx.x, tid = threadIdx.x;
    float inv = 1.f / den[b];
#pragma unroll
    for (int i = 0; i < Lsz / 256; ++i) {
        size_t idx = (size_t)b * Lsz + i * 256 + tid;
        wout[idx] = __expf(scores[idx]) * inv;
    }
    int d0 = tid * 2;
    ctx[(size_t)b * Dsz + d0]     = ctx_acc[b * Dsz + d0] * inv;
    ctx[(size_t)b * Dsz + d0 + 1] = ctx_acc[b * Dsz + d0 + 1] * inv;
}

extern "C" void kernel_launch(void* const* d_in, const int* in_sizes, int n_in,
                              void* d_out, int out_size, void* d_ws, size_t ws_size,
                              hipStream_t stream) {
    const float* feat   = (const float*)d_in[0];
    const float* hidden = (const float*)d_in[1];
    const float* W1     = (const float*)d_in[2];
    const float* W1b    = (const float*)d_in[3];
    const float* W2     = (const float*)d_in[4];
    const float* W2b    = (const float*)d_in[5];
    const float* Vk     = (const float*)d_in[6];
    const float* Vb     = (const float*)d_in[7];

    unsigned short* w1t = (unsigned short*)d_ws;
    float* hproj   = (float*)((char*)d_ws + 256 * 1024);
    float* scores  = (float*)((char*)d_ws + 320 * 1024);
    float* ctx_acc = (float*)((char*)d_ws + 1344 * 1024);
    float* den     = (float*)((char*)d_ws + 1472 * 1024);

    float* ctx  = (float*)d_out;              // [64, 512]
    float* wout = ctx + Bsz * Dsz;            // [64, 4096, 1]

    // zero ctx_acc + den (contiguous: 128KiB + 256B)
    hipMemsetAsync(ctx_acc, 0, Bsz * Dsz * sizeof(float) + Bsz * sizeof(float), stream);
    k_prep_w1t<<<512, 256, 0, stream>>>(W1, w1t);
    k_hproj<<<Bsz, Usz, 0, stream>>>(hidden, W2, W2b, W1b, hproj);
    k_score_ctx<<<dim3(Lsz / LT, Bsz), 256, 0, stream>>>(feat, w1t, hproj, Vk, Vb,
                                                         scores, ctx_acc, den);
    k_finalize<<<Bsz, 256, 0, stream>>>(scores, ctx_acc, den, ctx, wout);
}

// Round 3
// 207.342 us; speedup vs baseline: 1.8743x; 1.1353x over previous
//
#include <hip/hip_runtime.h>

#define Bsz 64
#define Lsz 4096
#define Dsz 512
#define Hsz 512
#define Usz 256
#define LT  64
#define NLB (Lsz / LT)       // 64 L-blocks per batch

typedef __attribute__((ext_vector_type(8))) short s8v;     // bf16x8 MFMA frag
typedef __attribute__((ext_vector_type(4))) float f4v;
typedef __attribute__((ext_vector_type(4))) unsigned short u16x4;

// XOR swizzle: c in shorts, 16B (8-short) granule rotated by row&7
#define SWZ(row, c) ((c) ^ (((row) & 7) << 3))

__device__ __forceinline__ unsigned short f2bf(float f) {
    unsigned int u = __float_as_uint(f);
    u += 0x7FFFu + ((u >> 16) & 1u);   // RNE
    return (unsigned short)(u >> 16);
}
__device__ __forceinline__ float bf2f(unsigned int lo16) {
    return __uint_as_float(lo16 << 16);
}

// ws layout
//   [0,     256K) : W1T bf16 [256][512]
//   [256K,  512K) : hp_part f32 [4][64][256]
//   [512K, 1536K) : el_arr f32 [64][4096]   (exp(score))
//   [1536K,1552K) : eden f32 [64][64]
//   [1552K,9744K) : pctx f32 [64][64][512]

// blocks 0..511: W1 -> W1T (bf16, transposed). blocks 512..767: hproj split-K partials.
__global__ __launch_bounds__(256) void k_prep(const float* __restrict__ W1,
                                              const float* __restrict__ hidden,
                                              const float* __restrict__ W2,
                                              unsigned short* __restrict__ W1T,
                                              float* __restrict__ hp_part) {
    int blk = blockIdx.x, tid = threadIdx.x;
    if (blk < 512) {
        int e = blk * 256 + tid;          // coalesced over W1 [512][256]
        int k = e >> 8, u = e & 255;
        W1T[u * Dsz + k] = f2bf(W1[e]);
    } else {
        int idx = blk - 512;
        int kq = idx >> 6, b = idx & 63;  // K-quarter, batch
        const float* hrow = hidden + (size_t)b * Hsz + kq * 128;
        const float* w2p  = W2 + (size_t)(kq * 128) * Usz + tid;
        float a0 = 0.f, a1 = 0.f, a2 = 0.f, a3 = 0.f;
#pragma unroll 8
        for (int k = 0; k < 128; k += 4) {
            a0 = fmaf(hrow[k + 0], w2p[(size_t)(k + 0) * Usz], a0);
            a1 = fmaf(hrow[k + 1], w2p[(size_t)(k + 1) * Usz], a1);
            a2 = fmaf(hrow[k + 2], w2p[(size_t)(k + 2) * Usz], a2);
            a3 = fmaf(hrow[k + 3], w2p[(size_t)(k + 3) * Usz], a3);
        }
        hp_part[((size_t)kq * Bsz + b) * Usz + tid] = (a0 + a1) + (a2 + a3);
    }
}

// Fused per (b, 64 L-rows): score -> exp -> partial den + partial ctx. No atomics.
__global__ __launch_bounds__(512, 4) void k_score_ctx(
    const float* __restrict__ feat, const unsigned short* __restrict__ W1T,
    const float* __restrict__ hp_part, const float* __restrict__ W1b,
    const float* __restrict__ W2b, const float* __restrict__ Vk,
    const float* __restrict__ Vb, float* __restrict__ el_arr,
    float* __restrict__ eden, float* __restrict__ pctx)
{
    __shared__ __align__(16) unsigned short A[LT][Dsz];   // 64 KiB, XOR-swizzled rows
    __shared__ float hp[Usz];
    __shared__ float vv[Usz];
    __shared__ float spart[8][LT];
    __shared__ float el[LT];
    __shared__ float pc[2][Dsz];

    const int tid  = threadIdx.x;
    const int w    = tid >> 6;
    const int lane = tid & 63;
    const int lr   = lane & 15;
    const int lg   = lane >> 4;
    const int b    = blockIdx.y;
    const int lb   = blockIdx.x;
    const int l0   = lb * LT;

    if (tid < Usz) {
        const float* hpb = hp_part + (size_t)b * Usz + tid;
        hp[tid] = (hpb[0] + hpb[Bsz * Usz]) + (hpb[2 * Bsz * Usz] + hpb[3 * Bsz * Usz])
                + W1b[tid] + W2b[tid];
        vv[tid] = Vk[tid];
    }

    // ---- stage 64x512 fp32 -> bf16 into swizzled LDS ----
    const float* fb = feat + (size_t)(b * Lsz + l0) * Dsz;
#pragma unroll 8
    for (int i = 0; i < 16; ++i) {
        int q   = i * 512 + tid;            // float4 index over 64*128
        int row = q >> 7, c4 = (q & 127) * 4;
        f4v v = *reinterpret_cast<const f4v*>(fb + (size_t)row * Dsz + c4);
        u16x4 o = { f2bf(v.x), f2bf(v.y), f2bf(v.z), f2bf(v.w) };
        *reinterpret_cast<u16x4*>(&A[row][SWZ(row, c4)]) = o;
    }
    __syncthreads();

    // ---- GEMM: 64 rows x this wave's 32 cols x K=512, depth-2 B prefetch ----
    const unsigned short* bp0 = W1T + (size_t)(w * 32 + lr) * Dsz + lg * 8;
    const unsigned short* bp1 = bp0 + 16 * Dsz;

    f4v acc[4][2];
#pragma unroll
    for (int mf = 0; mf < 4; ++mf) {
        acc[mf][0] = (f4v){0.f, 0.f, 0.f, 0.f};
        acc[mf][1] = (f4v){0.f, 0.f, 0.f, 0.f};
    }

    s8v b0c = *reinterpret_cast<const s8v*>(bp0);
    s8v b1c = *reinterpret_cast<const s8v*>(bp1);
    s8v b0n = *reinterpret_cast<const s8v*>(bp0 + 32);
    s8v b1n = *reinterpret_cast<const s8v*>(bp1 + 32);

#pragma unroll
    for (int ks = 0; ks < 16; ++ks) {
        s8v b0nn, b1nn;
        if (ks < 14) {
            b0nn = *reinterpret_cast<const s8v*>(bp0 + (ks + 2) * 32);
            b1nn = *reinterpret_cast<const s8v*>(bp1 + (ks + 2) * 32);
        }
        const int kof = ks * 32 + lg * 8;
#pragma unroll
        for (int mf = 0; mf < 4; ++mf) {
            const int row = mf * 16 + lr;
            s8v a = *reinterpret_cast<const s8v*>(&A[row][SWZ(row, kof)]);
            acc[mf][0] = __builtin_amdgcn_mfma_f32_16x16x32_bf16(a, b0c, acc[mf][0], 0, 0, 0);
            acc[mf][1] = __builtin_amdgcn_mfma_f32_16x16x32_bf16(a, b1c, acc[mf][1], 0, 0, 0);
        }
        b0c = b0n; b1c = b1n;
        if (ks < 14) { b0n = b0nn; b1n = b1nn; }
    }

    // ---- epilogue: per-row sum over this wave's 32 cols of tanh(x)*V ----
    float rs[4][4];
#pragma unroll
    for (int mf = 0; mf < 4; ++mf)
#pragma unroll
        for (int r = 0; r < 4; ++r) rs[mf][r] = 0.f;

#pragma unroll
    for (int mf = 0; mf < 4; ++mf) {
#pragma unroll
        for (int nf = 0; nf < 2; ++nf) {
            int col = w * 32 + nf * 16 + lr;
            float hpv = hp[col], vvv = vv[col];
#pragma unroll
            for (int r = 0; r < 4; ++r) {
                float x = acc[mf][nf][r] + hpv;
                float e = __expf(2.f * x);
                float t = 1.f - 2.f / (e + 1.f);     // tanh, safe at +/-inf
                rs[mf][r] = fmaf(t, vvv, rs[mf][r]);
            }
        }
    }
#pragma unroll
    for (int off = 1; off < 16; off <<= 1)
#pragma unroll
        for (int mf = 0; mf < 4; ++mf)
#pragma unroll
            for (int r = 0; r < 4; ++r)
                rs[mf][r] += __shfl_xor(rs[mf][r], off, 64);

    if (lr == 0) {
#pragma unroll
        for (int mf = 0; mf < 4; ++mf)
#pragma unroll
            for (int r = 0; r < 4; ++r)
                spart[w][mf * 16 + lg * 4 + r] = rs[mf][r];
    }
    __syncthreads();

    // ---- scores -> exp -> block denominator ----
    if (tid < LT) {
        float s = Vb[0];
#pragma unroll
        for (int ww = 0; ww < 8; ++ww) s += spart[ww][tid];
        float e = __expf(s);
        el_arr[(size_t)b * Lsz + l0 + tid] = e;
        el[tid] = e;
        float esum = e;
#pragma unroll
        for (int off = 1; off < 64; off <<= 1) esum += __shfl_xor(esum, off, 64);
        if (tid == 0) eden[b * NLB + lb] = esum;
    }
    __syncthreads();

    // ---- partial context from swizzled LDS tile ----
    {
        const int half = tid >> 8;              // rows [half*32, half*32+32)
        const int d0   = (tid & 255) * 2;
        float a0 = 0.f, a1 = 0.f;
#pragma unroll 8
        for (int li = 0; li < 32; ++li) {
            int l = half * 32 + li;
            unsigned int pk = *reinterpret_cast<const unsigned int*>(&A[l][SWZ(l, d0)]);
            float e = el[l];
            a0 = fmaf(e, bf2f(pk & 0xFFFFu), a0);
            a1 = fmaf(e, bf2f(pk >> 16), a1);
        }
        pc[half][d0]     = a0;
        pc[half][d0 + 1] = a1;
    }
    __syncthreads();
    pctx[((size_t)b * NLB + lb) * Dsz + tid] = pc[0][tid] + pc[1][tid];
}

__global__ __launch_bounds__(256) void k_finalize(const float* __restrict__ el_arr,
                                                  const float* __restrict__ eden,
                                                  const float* __restrict__ pctx,
                                                  float* __restrict__ ctx,
                                                  float* __restrict__ wout) {
    int b = blockIdx.x, tid = threadIdx.x;
    // every wave reduces the 64 partial denominators
    float s = eden[b * NLB + (tid & 63)];
#pragma unroll
    for (int off = 1; off < 64; off <<= 1) s += __shfl_xor(s, off, 64);
    float inv = 1.f / s;

    int d = tid * 2;
    float c0 = 0.f, c1 = 0.f;
#pragma unroll 8
    for (int lbi = 0; lbi < NLB; ++lbi) {
        const float* p = pctx + ((size_t)b * NLB + lbi) * Dsz + d;
        c0 += p[0];
        c1 += p[1];
    }
    ctx[(size_t)b * Dsz + d]     = c0 * inv;
    ctx[(size_t)b * Dsz + d + 1] = c1 * inv;

#pragma unroll
    for (int i = 0; i < Lsz / 256; ++i) {
        size_t idx = (size_t)b * Lsz + i * 256 + tid;
        wout[idx] = el_arr[idx] * inv;
    }
}

extern "C" void kernel_launch(void* const* d_in, const int* in_sizes, int n_in,
                              void* d_out, int out_size, void* d_ws, size_t ws_size,
                              hipStream_t stream) {
    const float* feat   = (const float*)d_in[0];
    const float* hidden = (const float*)d_in[1];
    const float* W1     = (const float*)d_in[2];
    const float* W1b    = (const float*)d_in[3];
    const float* W2     = (const float*)d_in[4];
    const float* W2b    = (const float*)d_in[5];
    const float* Vk     = (const float*)d_in[6];
    const float* Vb     = (const float*)d_in[7];

    unsigned short* w1t = (unsigned short*)d_ws;
    float* hp_part = (float*)((char*)d_ws + 256 * 1024);
    float* el_arr  = (float*)((char*)d_ws + 512 * 1024);
    float* eden    = (float*)((char*)d_ws + 1536 * 1024);
    float* pctx    = (float*)((char*)d_ws + 1552 * 1024);

    float* ctx  = (float*)d_out;              // [64, 512]
    float* wout = ctx + Bsz * Dsz;            // [64, 4096, 1]

    k_prep<<<768, 256, 0, stream>>>(W1, hidden, W2, w1t, hp_part);
    k_score_ctx<<<dim3(NLB, Bsz), 512, 0, stream>>>(feat, w1t, hp_part, W1b, W2b,
                                                    Vk, Vb, el_arr, eden, pctx);
    k_finalize<<<Bsz, 256, 0, stream>>>(el_arr, eden, pctx, ctx, wout);
}